// Round 4
// baseline (583.801 us; speedup 1.0000x reference)
//
#include <hip/hip_runtime.h>
#include <math.h>

typedef __attribute__((ext_vector_type(8)))  short short8;
typedef __attribute__((ext_vector_type(16))) float f32x16;

#define NPLANE 48
#define H 512
#define W 512
#define TH 21
#define OH 492
#define OW 492
#define EPSF 1e-8f

#define STRIDE 168   // LDS row stride in shorts (measured ~conflict-free)
#define SEG_ROWS 84  // 64 output rows + 20 halo

// d_ws layout (bytes) — total ~4.13 MB:
//   [0)        B_corr : 48 * 21 * 4 * 512 bf16 = 4,128,768 B (frag-swizzled)
//   [4128768)  B_ones : 4 * 512 bf16 = 4096 B
#define BONES_HOFF (4128768u / 2)

__device__ inline unsigned short f2bf(float f) {
    unsigned u = __float_as_uint(f);
    return (unsigned short)((u + 0x7FFFu + ((u >> 16) & 1u)) >> 16);
}
__device__ inline float bf2f(unsigned s) {
    return __uint_as_float(s << 16);
}
// Packed RNE f32x2 -> bf16x2; identical rounding to f2bf, 1 VALU op.
__device__ inline unsigned cvtpk(float lo, float hi) {
    unsigned r;
    asm("v_cvt_pk_bf16_f32 %0, %1, %2" : "=v"(r) : "v"(lo), "v"(hi));
    return r;
}

// ---------------------------------------------------------------------------
// K0: template z-norm (/441 folded) -> Toeplitz B fragments (unchanged).
// ---------------------------------------------------------------------------
__global__ void build_b_kernel(const float* __restrict__ tpl,
                               unsigned short* __restrict__ ws16) {
    __shared__ float sm[2];
    const int plane = blockIdx.x;
    const float* t = tpl + plane * 441;
    const int tid = threadIdx.x;
    if (tid < 64) {
        float s = 0.f, s2 = 0.f;
        for (int k = tid; k < 441; k += 64) {
            float x = t[k];
            s += x; s2 += x * x;
        }
#pragma unroll
        for (int o = 32; o >= 1; o >>= 1) {
            s  += __shfl_down(s, o);
            s2 += __shfl_down(s2, o);
        }
        if (tid == 0) {
            float mean = s / 441.f;
            float var = fmaxf(s2 / 441.f - mean * mean, 0.f);
            sm[0] = mean;
            sm[1] = 1.f / ((sqrtf(var) + EPSF) * 441.f);
        }
    }
    __syncthreads();
    const float mean = sm[0], scale = sm[1];

    unsigned short* bc = ws16 + (size_t)plane * 43008;
    for (int i = tid; i < 43008; i += 256) {
        int j = i & 7, lane = (i >> 3) & 63, s = (i >> 9) & 3, u = i >> 11;
        int k = ((lane >> 5) << 3) + j, n = lane & 31;
        int v = 16 * s + k - n;
        float val = (v >= 0 && v < TH) ? (t[u * 21 + v] - mean) * scale : 0.f;
        bc[i] = f2bf(val);
    }
    if (plane == 0) {
        unsigned short* bo = ws16 + BONES_HOFF;
        const unsigned short one = f2bf(1.f);
        for (int i = tid; i < 2048; i += 256) {
            int j = i & 7, lane = (i >> 3) & 63, s = (i >> 9) & 3;
            int k = ((lane >> 5) << 3) + j, n = lane & 31;
            int v = 16 * s + k - n;
            bo[i] = (v >= 0 && v < TH) ? one : (unsigned short)0;
        }
    }
}

// ---------------------------------------------------------------------------
// K1: fused NCC. R4: async-stage tile pipelining (T14) on top of R3.
// Grid y 8->4; each block does 2 y-tiles (y0 = by*128 + ty*64). Tile 1's
// global loads are issued into registers BEFORE tile 0's corr phase (corr's
// ~1.75 us hides HBM latency; the vmcnt(0) drain at the next barrier is then
// free) and written to seg after vpass(true)'s barrier — where seg has no
// readers until the next corr — concurrent with aQ + epilogue. Barrier count
// per tile unchanged (4).
// Epilogue: compute all 16 outputs into regs, then a tight back-to-back
// store burst (R3's interleaved 32-col stores from 4 waves stopped merging
// in L2: WRITE_SIZE 49 -> 77.6 MB).
// Structure otherwise = R3: 512 thr / 8 waves, one 32x32 tile per wave,
// LDS 49.7 KB, vpass on 320 threads, rsq epilogue, corr unrolled x2.
// ---------------------------------------------------------------------------
__global__ __launch_bounds__(512, 4) void ncc_fused_kernel(
    const float* __restrict__ in, const unsigned short* __restrict__ ws16,
    float* __restrict__ out) {
    __shared__ short seg[SEG_ROWS * STRIDE];   // 28224 B
    __shared__ short vbuf[64 * STRIDE];        // 21504 B  (total 49728 B)

    const int plane = blockIdx.z;
    const int x0 = blockIdx.x * 128;
    const int yb = blockIdx.y * 128;
    const int tid = threadIdx.x;
    const int lane = tid & 63;
    const int wid = tid >> 6;        // 0..7
    const int tr = wid & 1;          // tile-row (32-row band)
    const int tc = wid >> 1;         // tile-col (32-col band, 0..3)
    const float* src = in + (size_t)plane * H * W;

    // ---- prologue: stage tile 0 (84x160 fp32 -> bf16) directly into LDS ----
    for (int i = tid; i < SEG_ROWS * 20; i += 512) {
        int row = i / 20, s8 = i - row * 20;
        int gy = yb + row, gx = x0 + s8 * 8;
        if (gy < H && gx + 7 < W) {
            float4 a = *(const float4*)(src + gy * W + gx);
            float4 b = *(const float4*)(src + gy * W + gx + 4);
            uint4 v;
            v.x = cvtpk(a.x, a.y);
            v.y = cvtpk(a.z, a.w);
            v.z = cvtpk(b.x, b.y);
            v.w = cvtpk(b.z, b.w);
            *(uint4*)&seg[row * STRIDE + s8 * 8] = v;
        } else {
            short8 val;
#pragma unroll
            for (int e = 0; e < 8; ++e) {
                float xv = (gy < H && gx + e < W) ? src[gy * W + gx + e] : 0.f;
                val[e] = (short)f2bf(xv);
            }
            *(short8*)&seg[row * STRIDE + s8 * 8] = val;
        }
    }

    const int m = lane & 31;
    const int half = lane >> 5;
    // Shared row mapping for seg (corr A-reads) AND vbuf (box/aQ A-reads).
    const int abase = (tr * 32 + m) * STRIDE + tc * 32 + half * 8;
    const unsigned short* bc = ws16 + (size_t)plane * 43008 + lane * 8;

    // Bones fragments: load once per block (L2-hot), live in regs throughout.
    const unsigned short* bo16 = ws16 + BONES_HOFF + lane * 8;
    short8 bones[4];
#pragma unroll
    for (int s = 0; s < 4; ++s)
        bones[s] = *(const short8*)(bo16 + s * 512);

    __syncthreads();

    // ---- vertical 21-sum pass: 320 threads, 4 row-quarters x 80 col-pairs.
    auto vpass = [&](bool sq) {
        if (tid < 320) {
            const int q = tid / 80;              // row-quarter 0..3
            const int c2 = (tid - q * 80) * 2;   // col pair
            const int base = q * 16;
            float s0 = 0.f, s1 = 0.f;
#pragma unroll
            for (int r = 0; r < 20; ++r) {
                unsigned p = *(const unsigned*)&seg[(base + r) * STRIDE + c2];
                float a = bf2f(p & 0xffffu), b = bf2f(p >> 16);
                if (sq) { s0 = fmaf(a, a, s0); s1 = fmaf(b, b, s1); }
                else    { s0 += a; s1 += b; }
            }
#pragma unroll
            for (int yy = 0; yy < 16; yy += 8) {
                unsigned pin[8], pout[8];
#pragma unroll
                for (int r = 0; r < 8; ++r) {
                    pin[r]  = *(const unsigned*)
                        &seg[(base + yy + r + 20) * STRIDE + c2];
                    pout[r] = *(const unsigned*)
                        &seg[(base + yy + r) * STRIDE + c2];
                }
#pragma unroll
                for (int r = 0; r < 8; ++r) {
                    float a = bf2f(pin[r] & 0xffffu), b = bf2f(pin[r] >> 16);
                    if (sq) { s0 = fmaf(a, a, s0); s1 = fmaf(b, b, s1); }
                    else    { s0 += a; s1 += b; }
                    *(unsigned*)&vbuf[(base + yy + r) * STRIDE + c2] =
                        cvtpk(s0, s1);
                    float c = bf2f(pout[r] & 0xffffu), d = bf2f(pout[r] >> 16);
                    if (sq) { s0 = fmaf(-c, c, s0); s1 = fmaf(-d, d, s1); }
                    else    { s0 -= c; s1 -= d; }
                }
            }
        }
    };

    for (int ty = 0; ty < 2; ++ty) {
        const int y0 = yb + ty * 64;

        // ---- issue next tile's global loads into regs (no waits) ----
        float4 ldA[4], ldB[4];
        if (ty == 0) {
#pragma unroll
            for (int k = 0; k < 4; ++k) {
                ldA[k] = make_float4(0.f, 0.f, 0.f, 0.f);
                ldB[k] = make_float4(0.f, 0.f, 0.f, 0.f);
                int i = tid + k * 512;
                if (i < SEG_ROWS * 20) {
                    int row = i / 20, s8 = i - row * 20;
                    int gy = yb + 64 + row, gx = x0 + s8 * 8;
                    if (gy < H && gx + 7 < W) {
                        ldA[k] = *(const float4*)(src + gy * W + gx);
                        ldB[k] = *(const float4*)(src + gy * W + gx + 4);
                    } else {
                        float t[8];
#pragma unroll
                        for (int e = 0; e < 8; ++e)
                            t[e] = (gy < H && gx + e < W)
                                       ? src[gy * W + gx + e] : 0.f;
                        ldA[k] = make_float4(t[0], t[1], t[2], t[3]);
                        ldB[k] = make_float4(t[4], t[5], t[6], t[7]);
                    }
                }
            }
        }

        // ---- corr K-loop, unrolled x2 with ping-pong B buffers ----
        f32x16 acc;
#pragma unroll
        for (int e = 0; e < 16; ++e) acc[e] = 0.f;

        auto corr_step = [&](int u, short8* bf) {
            short8 af[4];
#pragma unroll
            for (int s = 0; s < 4; ++s)
                af[s] = *(const short8*)&seg[abase + u * STRIDE + s * 16];
#pragma unroll
            for (int s = 0; s < 4; ++s)
                acc = __builtin_amdgcn_mfma_f32_32x32x16_bf16(af[s], bf[s],
                                                              acc, 0, 0, 0);
        };

        short8 bA[4], bB[4];
#pragma unroll
        for (int s = 0; s < 4; ++s)
            bA[s] = *(const short8*)(bc + s * 512);

        for (int u = 0; u < TH - 1; u += 2) {
#pragma unroll
            for (int s = 0; s < 4; ++s)
                bB[s] = *(const short8*)(bc + ((u + 1) * 4 + s) * 512);
            corr_step(u, bA);
#pragma unroll
            for (int s = 0; s < 4; ++s)
                bA[s] = *(const short8*)(bc + ((u + 2) * 4 + s) * 512);
            corr_step(u + 1, bB);
        }
        corr_step(TH - 1, bA);

        // ---- phase schedule (4 barriers per tile) ----
        vpass(false);
        __syncthreads();                 // vbuf(sum) ready

        f32x16 aS;
#pragma unroll
        for (int e = 0; e < 16; ++e) aS[e] = 0.f;
#pragma unroll
        for (int s = 0; s < 4; ++s) {
            short8 vf = *(const short8*)&vbuf[abase + s * 16];
            aS = __builtin_amdgcn_mfma_f32_32x32x16_bf16(vf, bones[s], aS,
                                                         0, 0, 0);
        }
        __syncthreads();                 // all aS reads done

        vpass(true);
        __syncthreads();                 // vbuf(sq) ready; ALL seg reads done

        f32x16 aQ;
#pragma unroll
        for (int e = 0; e < 16; ++e) aQ[e] = 0.f;
#pragma unroll
        for (int s = 0; s < 4; ++s) {
            short8 qf = *(const short8*)&vbuf[abase + s * 16];
            aQ = __builtin_amdgcn_mfma_f32_32x32x16_bf16(qf, bones[s], aQ,
                                                         0, 0, 0);
        }

        // ---- write staged tile 1 -> seg (seg has no readers until next
        //      corr, which is after the barrier below) ----
        if (ty == 0) {
#pragma unroll
            for (int k = 0; k < 4; ++k) {
                int i = tid + k * 512;
                if (i < SEG_ROWS * 20) {
                    int row = i / 20, s8 = i - row * 20;
                    uint4 v;
                    v.x = cvtpk(ldA[k].x, ldA[k].y);
                    v.y = cvtpk(ldA[k].z, ldA[k].w);
                    v.z = cvtpk(ldB[k].x, ldB[k].y);
                    v.w = cvtpk(ldB[k].z, ldB[k].w);
                    *(uint4*)&seg[row * STRIDE + s8 * 8] = v;
                }
            }
        }

        // ---- normalize into regs, then tight store burst ----
        const float invn = 1.f / 441.f;
        float* outp = out + (size_t)plane * OH * OW;
        float vout[16];
#pragma unroll
        for (int r = 0; r < 16; ++r) {
            float mean = aS[r] * invn;
            float msq = aQ[r] * invn;
            float var = fmaf(-mean, mean, msq) + EPSF;
            vout[r] = acc[r] * __builtin_amdgcn_rsqf(var);
        }
        const int gx = x0 + tc * 32 + m;
        if (gx < OW) {
#pragma unroll
            for (int r = 0; r < 16; ++r) {
                int gy = y0 + tr * 32 + (r & 3) + ((r >> 2) << 3) + half * 4;
                if (gy < OH)
                    outp[(size_t)gy * OW + gx] = vout[r];
            }
        }

        __syncthreads();                 // seg(t+1) visible; vbuf free
    }
}

extern "C" void kernel_launch(void* const* d_in, const int* in_sizes, int n_in,
                              void* d_out, int out_size, void* d_ws,
                              size_t ws_size, hipStream_t stream) {
    const float* inputs = (const float*)d_in[0];
    const float* tmpl = (const float*)d_in[1];
    float* out = (float*)d_out;
    unsigned short* ws16 = (unsigned short*)d_ws;

    build_b_kernel<<<NPLANE, 256, 0, stream>>>(tmpl, ws16);
    ncc_fused_kernel<<<dim3(4, 4, NPLANE), 512, 0, stream>>>(inputs, ws16, out);
}

// Round 5
// 166.015 us; speedup vs baseline: 3.5166x; 3.5166x over previous
//
#include <hip/hip_runtime.h>
#include <math.h>

typedef __attribute__((ext_vector_type(8)))  short short8;
typedef __attribute__((ext_vector_type(16))) float f32x16;

#define NPLANE 48
#define H 512
#define W 512
#define TH 21
#define OH 492
#define OW 492
#define EPSF 1e-8f

#define STRIDE 168   // LDS row stride in shorts (measured ~conflict-free)
#define SEG_ROWS 84  // 64 output rows + 20 halo

// d_ws layout (bytes) — total ~4.13 MB:
//   [0)        B_corr : 48 * 21 * 4 * 512 bf16 = 4,128,768 B (frag-swizzled)
//   [4128768)  B_ones : 4 * 512 bf16 = 4096 B
#define BONES_HOFF (4128768u / 2)

__device__ inline unsigned short f2bf(float f) {
    unsigned u = __float_as_uint(f);
    return (unsigned short)((u + 0x7FFFu + ((u >> 16) & 1u)) >> 16);
}
__device__ inline float bf2f(unsigned s) {
    return __uint_as_float(s << 16);
}
// Packed RNE f32x2 -> bf16x2; identical rounding to f2bf, 1 VALU op.
__device__ inline unsigned cvtpk(float lo, float hi) {
    unsigned r;
    asm("v_cvt_pk_bf16_f32 %0, %1, %2" : "=v"(r) : "v"(lo), "v"(hi));
    return r;
}

// ---------------------------------------------------------------------------
// K0: template z-norm (/441 folded) -> Toeplitz B fragments (unchanged).
// ---------------------------------------------------------------------------
__global__ void build_b_kernel(const float* __restrict__ tpl,
                               unsigned short* __restrict__ ws16) {
    __shared__ float sm[2];
    const int plane = blockIdx.x;
    const float* t = tpl + plane * 441;
    const int tid = threadIdx.x;
    if (tid < 64) {
        float s = 0.f, s2 = 0.f;
        for (int k = tid; k < 441; k += 64) {
            float x = t[k];
            s += x; s2 += x * x;
        }
#pragma unroll
        for (int o = 32; o >= 1; o >>= 1) {
            s  += __shfl_down(s, o);
            s2 += __shfl_down(s2, o);
        }
        if (tid == 0) {
            float mean = s / 441.f;
            float var = fmaxf(s2 / 441.f - mean * mean, 0.f);
            sm[0] = mean;
            sm[1] = 1.f / ((sqrtf(var) + EPSF) * 441.f);
        }
    }
    __syncthreads();
    const float mean = sm[0], scale = sm[1];

    unsigned short* bc = ws16 + (size_t)plane * 43008;
    for (int i = tid; i < 43008; i += 256) {
        int j = i & 7, lane = (i >> 3) & 63, s = (i >> 9) & 3, u = i >> 11;
        int k = ((lane >> 5) << 3) + j, n = lane & 31;
        int v = 16 * s + k - n;
        float val = (v >= 0 && v < TH) ? (t[u * 21 + v] - mean) * scale : 0.f;
        bc[i] = f2bf(val);
    }
    if (plane == 0) {
        unsigned short* bo = ws16 + BONES_HOFF;
        const unsigned short one = f2bf(1.f);
        for (int i = tid; i < 2048; i += 256) {
            int j = i & 7, lane = (i >> 3) & 63, s = (i >> 9) & 3;
            int k = ((lane >> 5) << 3) + j, n = lane & 31;
            int v = 16 * s + k - n;
            bo[i] = (v >= 0 && v < TH) ? one : (unsigned short)0;
        }
    }
}

// ---------------------------------------------------------------------------
// K1: fused NCC. R5: phase-overlap restructure.
// Evidence (R3): sum of pipe times (MFMA 15 + VALU 14 + LDS ~20 + HBM ~17 us)
// ~= measured 70 us -> pipes are phase-serialized by the barrier schedule.
// vpass(sum)/vpass(sq) depend ONLY on seg, not on corr, so:
//  * vbuf split into vsum + vsq (LDS 49.7 -> 71.2 KB, still 2 blocks/CU).
//  * Each wave runs corr then its 1/8 slice of BOTH vpasses with NO barrier
//    between -- wave drift overlaps corr's MFMA/LDS with vpass VALU.
//  * Barriers 4 -> 2 (after stage, after corr+vpass). aS and aQ issue
//    together in the single epilogue phase.
//  * R4's reg-compute + tight store burst kept (WRITE_SIZE fix); R4's
//    register prefetch DROPPED (it spilled: FETCH 593 MB, 506 us).
// vpass partition: 640 units = pass(2) x quarter(4) x colpair(80); wave w
// owns units [80w, 80w+80): lane takes 80w+lane, lanes 0-15 also 80w+64+lane.
// p,q are wave-uniform (no divergence); c2 stride-4B -> 2-way bank = free.
// ---------------------------------------------------------------------------
__global__ __launch_bounds__(512, 4) void ncc_fused_kernel(
    const float* __restrict__ in, const unsigned short* __restrict__ ws16,
    float* __restrict__ out) {
    __shared__ short seg[SEG_ROWS * STRIDE];   // 28224 B
    __shared__ short vsum[64 * STRIDE];        // 21504 B
    __shared__ short vsq[64 * STRIDE];         // 21504 B  (total 71232 B)

    const int plane = blockIdx.z;
    const int x0 = blockIdx.x * 128;
    const int y0 = blockIdx.y * 64;
    const int tid = threadIdx.x;
    const int lane = tid & 63;
    const int wid = tid >> 6;        // 0..7
    const int tr = wid & 1;          // tile-row (32-row band)
    const int tc = wid >> 1;         // tile-col (32-col band, 0..3)
    const float* src = in + (size_t)plane * H * W;

    // ---- stage 84x160 fp32 -> bf16 into LDS (cvt_pk packing) ----
    for (int i = tid; i < SEG_ROWS * 20; i += 512) {
        int row = i / 20, s8 = i - row * 20;
        int gy = y0 + row, gx = x0 + s8 * 8;
        if (gy < H && gx + 7 < W) {
            float4 a = *(const float4*)(src + gy * W + gx);
            float4 b = *(const float4*)(src + gy * W + gx + 4);
            uint4 v;
            v.x = cvtpk(a.x, a.y);
            v.y = cvtpk(a.z, a.w);
            v.z = cvtpk(b.x, b.y);
            v.w = cvtpk(b.z, b.w);
            *(uint4*)&seg[row * STRIDE + s8 * 8] = v;
        } else {
            short8 val;
#pragma unroll
            for (int e = 0; e < 8; ++e) {
                float xv = (gy < H && gx + e < W) ? src[gy * W + gx + e] : 0.f;
                val[e] = (short)f2bf(xv);
            }
            *(short8*)&seg[row * STRIDE + s8 * 8] = val;
        }
    }

    const int m = lane & 31;
    const int half = lane >> 5;
    // Shared row mapping for seg (corr A-reads) AND vsum/vsq (box A-reads).
    const int abase = (tr * 32 + m) * STRIDE + tc * 32 + half * 8;
    const unsigned short* bc = ws16 + (size_t)plane * 43008 + lane * 8;

    // Bones fragments: load once (L2-hot), live in regs to the epilogue.
    const unsigned short* bo16 = ws16 + BONES_HOFF + lane * 8;
    short8 bones[4];
#pragma unroll
    for (int s = 0; s < 4; ++s)
        bones[s] = *(const short8*)(bo16 + s * 512);

    __syncthreads();                 // seg ready

    // ---- corr K-loop, unrolled x2 with ping-pong B buffers ----
    f32x16 acc;
#pragma unroll
    for (int e = 0; e < 16; ++e) acc[e] = 0.f;

    auto corr_step = [&](int u, short8* bf) {
        short8 af[4];
#pragma unroll
        for (int s = 0; s < 4; ++s)
            af[s] = *(const short8*)&seg[abase + u * STRIDE + s * 16];
#pragma unroll
        for (int s = 0; s < 4; ++s)
            acc = __builtin_amdgcn_mfma_f32_32x32x16_bf16(af[s], bf[s], acc,
                                                          0, 0, 0);
    };

    short8 bA[4], bB[4];
#pragma unroll
    for (int s = 0; s < 4; ++s)
        bA[s] = *(const short8*)(bc + s * 512);

    for (int u = 0; u < TH - 1; u += 2) {
#pragma unroll
        for (int s = 0; s < 4; ++s)
            bB[s] = *(const short8*)(bc + ((u + 1) * 4 + s) * 512);
        corr_step(u, bA);
#pragma unroll
        for (int s = 0; s < 4; ++s)
            bA[s] = *(const short8*)(bc + ((u + 2) * 4 + s) * 512);
        corr_step(u + 1, bB);
    }
    corr_step(TH - 1, bA);

    // ---- vpass slice (NO barrier since corr: only seg-reads, vsum/vsq
    //      writes; readers of vsum/vsq are after the next barrier) ----
    auto unit = [&](int U) {
        const int p = U / 320;               // 0 = sum, 1 = sum-of-squares
        const int rem = U - p * 320;
        const int q = rem / 80;              // row-quarter 0..3
        const int c2 = (rem - q * 80) * 2;   // col pair
        const int base = q * 16;
        short* dst = p ? vsq : vsum;
        float s0 = 0.f, s1 = 0.f;
#pragma unroll
        for (int r = 0; r < 20; ++r) {
            unsigned pk = *(const unsigned*)&seg[(base + r) * STRIDE + c2];
            float a = bf2f(pk & 0xffffu), b = bf2f(pk >> 16);
            if (p) { s0 = fmaf(a, a, s0); s1 = fmaf(b, b, s1); }
            else   { s0 += a; s1 += b; }
        }
#pragma unroll
        for (int yy = 0; yy < 16; yy += 8) {
            unsigned pin[8], pout[8];
#pragma unroll
            for (int r = 0; r < 8; ++r) {
                pin[r]  = *(const unsigned*)
                    &seg[(base + yy + r + 20) * STRIDE + c2];
                pout[r] = *(const unsigned*)
                    &seg[(base + yy + r) * STRIDE + c2];
            }
#pragma unroll
            for (int r = 0; r < 8; ++r) {
                float a = bf2f(pin[r] & 0xffffu), b = bf2f(pin[r] >> 16);
                if (p) { s0 = fmaf(a, a, s0); s1 = fmaf(b, b, s1); }
                else   { s0 += a; s1 += b; }
                *(unsigned*)&dst[(base + yy + r) * STRIDE + c2] =
                    cvtpk(s0, s1);
                float c = bf2f(pout[r] & 0xffffu), d = bf2f(pout[r] >> 16);
                if (p) { s0 = fmaf(-c, c, s0); s1 = fmaf(-d, d, s1); }
                else   { s0 -= c; s1 -= d; }
            }
        }
    };

    unit(wid * 80 + lane);
    if (lane < 16) unit(wid * 80 + 64 + lane);

    __syncthreads();                 // vsum + vsq ready

    // ---- aS + aQ (8 MFMAs, one phase), normalize, tight store burst ----
    f32x16 aS, aQ;
#pragma unroll
    for (int e = 0; e < 16; ++e) { aS[e] = 0.f; aQ[e] = 0.f; }
#pragma unroll
    for (int s = 0; s < 4; ++s) {
        short8 vf = *(const short8*)&vsum[abase + s * 16];
        short8 qf = *(const short8*)&vsq[abase + s * 16];
        aS = __builtin_amdgcn_mfma_f32_32x32x16_bf16(vf, bones[s], aS,
                                                     0, 0, 0);
        aQ = __builtin_amdgcn_mfma_f32_32x32x16_bf16(qf, bones[s], aQ,
                                                     0, 0, 0);
    }

    const float invn = 1.f / 441.f;
    float* outp = out + (size_t)plane * OH * OW;
    float vout[16];
#pragma unroll
    for (int r = 0; r < 16; ++r) {
        float mean = aS[r] * invn;
        float msq = aQ[r] * invn;
        float var = fmaf(-mean, mean, msq) + EPSF;
        vout[r] = acc[r] * __builtin_amdgcn_rsqf(var);
    }
    const int gx = x0 + tc * 32 + m;
    if (gx < OW) {
#pragma unroll
        for (int r = 0; r < 16; ++r) {
            int gy = y0 + tr * 32 + (r & 3) + ((r >> 2) << 3) + half * 4;
            if (gy < OH)
                outp[(size_t)gy * OW + gx] = vout[r];
        }
    }
}

extern "C" void kernel_launch(void* const* d_in, const int* in_sizes, int n_in,
                              void* d_out, int out_size, void* d_ws,
                              size_t ws_size, hipStream_t stream) {
    const float* inputs = (const float*)d_in[0];
    const float* tmpl = (const float*)d_in[1];
    float* out = (float*)d_out;
    unsigned short* ws16 = (unsigned short*)d_ws;

    build_b_kernel<<<NPLANE, 256, 0, stream>>>(tmpl, ws16);
    ncc_fused_kernel<<<dim3(4, 8, NPLANE), 512, 0, stream>>>(inputs, ws16, out);
}